// Round 10
// baseline (191.660 us; speedup 1.0000x reference)
//
#include <hip/hip_runtime.h>

#define BB  64
#define TT  1024
#define CC  256
#define PP  784     // 28*28
#define HID 512
#define FF  1280    // CC + TT

typedef float v4f __attribute__((ext_vector_type(4)));
typedef short v8s __attribute__((ext_vector_type(8)));

// round-to-nearest-even bf16; returns the f32 bit pattern of the bf16 value
__device__ inline unsigned int bf16_rne_bits(float x) {
    unsigned int u = __float_as_uint(x);
    unsigned int r = u + 0x7FFFu + ((u >> 16) & 1u);
    return r & 0xFFFF0000u;
}

// barrier that does NOT drain vmcnt: LDS-visibility only (T4 essence).
// In-flight global loads survive across it; compiler's counted vmcnt waits
// handle the register uses.
__device__ inline void barrier_lds_only() {
    asm volatile("s_waitcnt lgkmcnt(0)" ::: "memory");
    __builtin_amdgcn_s_barrier();
}

// ---------------------------------------------------------------------------
// K0: W1 vision-half -> bf16 hi/lo, fragment-image order, full-512h chunks:
// chunk ks (16384 elems) holds h*32 + g*8 + e, where c = ks*32 + g*8 + e.
// ---------------------------------------------------------------------------
__global__ __launch_bounds__(256) void k_w1t(const float* __restrict__ W1,
                                             unsigned short* __restrict__ w1t_hi,
                                             unsigned short* __restrict__ w1t_lo) {
    const int id = blockIdx.x * 256 + threadIdx.x;   // 16384 threads
    const int ks = id >> 11;          // 0..7
    const int h  = (id >> 2) & 511;
    const int g  = id & 3;
    const float* W1v = W1 + (size_t)TT * HID;
    unsigned int hw[4], lw[4];
    #pragma unroll
    for (int k = 0; k < 4; ++k) {
        const int c0 = ks * 32 + g * 8 + 2 * k;
        float x0 = W1v[(size_t)c0 * HID + h];
        float x1 = W1v[(size_t)(c0 + 1) * HID + h];
        unsigned int h0 = bf16_rne_bits(x0), h1 = bf16_rne_bits(x1);
        unsigned int l0 = bf16_rne_bits(x0 - __uint_as_float(h0));
        unsigned int l1 = bf16_rne_bits(x1 - __uint_as_float(h1));
        hw[k] = (h0 >> 16) | (h1 & 0xFFFF0000u);
        lw[k] = (l0 >> 16) | (l1 & 0xFFFF0000u);
    }
    *(int4*)(&w1t_hi[(size_t)id * 8]) = make_int4(hw[0], hw[1], hw[2], hw[3]);
    *(int4*)(&w1t_lo[(size_t)id * 8]) = make_int4(lw[0], lw[1], lw[2], lw[3]);
}

// ---------------------------------------------------------------------------
// K1: text GEMM partials, k-split by 8 (unchanged).
// ---------------------------------------------------------------------------
__global__ __launch_bounds__(512) void k_text_gemm(const float* __restrict__ text,
                                                   const float* __restrict__ W1,
                                                   float* __restrict__ tbp) {
    const int b  = blockIdx.x;
    const int ks = blockIdx.y;    // 0..7
    const int t  = threadIdx.x;
    __shared__ float st[128];
    if (t < 128) st[t] = text[b * TT + ks * 128 + t];
    __syncthreads();
    float acc = 0.f;
    const float* wp = W1 + (size_t)(ks * 128) * HID + t;
    #pragma unroll 4
    for (int k = 0; k < 128; ++k)
        acc = fmaf(st[k], wp[(size_t)k * HID], acc);
    tbp[(b * 8 + ks) * HID + t] = acc;
}

// ---------------------------------------------------------------------------
// K2 (hot): vision GEMM, bf16 hi/lo 3-term MFMA. 1024-thr block = full
// HID=512 tile (no hh split -> vision loaded once, no global atomics).
// 16 waves, wave = 7m x 2n -> acc 56 regs -> ~128 unified -> 4 waves/SIMD.
// A double-buffered in LDS; loads issued 2 steps ahead and kept in flight
// across barrier_lds_only() (no vmcnt drain). 3-term MFMAs pass-split so
// every acc reuse has >=7 independent MFMAs between (no dep stall).
// ---------------------------------------------------------------------------
__global__ __launch_bounds__(1024, 4) void k_vision_mfma(
        const float* __restrict__ vision,
        const unsigned short* __restrict__ w1t_hi,
        const unsigned short* __restrict__ w1t_lo,
        const float* __restrict__ b1,
        const float* __restrict__ W2,
        const float* __restrict__ tbp,
        float* __restrict__ scores) {
    const int ptile = blockIdx.x;   // 0..6
    const int b     = blockIdx.y;
    const int tid   = threadIdx.x;
    const int lane  = tid & 63;
    const int w     = tid >> 6;     // 0..15
    const int l15   = lane & 15, lg = lane >> 4;

    __shared__ char albuf[2][14336];     // [buf][hi 7168 | lo 7168]
    __shared__ float sred[16 * 112];

    v4f acc[7][2];
    #pragma unroll
    for (int m = 0; m < 7; ++m) {
        acc[m][0] = (v4f){0.f, 0.f, 0.f, 0.f};
        acc[m][1] = (v4f){0.f, 0.f, 0.f, 0.f};
    }

    const size_t vbase = (size_t)b * (CC * PP) + ptile * 112;
    const int spx = tid >> 3;           // 0..127, valid < 112
    const int scg = tid & 7;            // 4 c's each
    const bool stg = (tid < 896);

    float xa[4], xb[4];

    #define A_LOAD(XV, KS) do { \
        _Pragma("unroll") for (int j = 0; j < 4; ++j) { \
            const int c_ = (KS) * 32 + scg * 4 + j; \
            XV[j] = vision[vbase + (size_t)c_ * PP + spx]; } } while (0)

    #define A_WRITE(BUF, XV) do { \
        unsigned int h0_ = bf16_rne_bits(XV[0]); \
        unsigned int h1_ = bf16_rne_bits(XV[1]); \
        unsigned int h2_ = bf16_rne_bits(XV[2]); \
        unsigned int h3_ = bf16_rne_bits(XV[3]); \
        unsigned int l0_ = bf16_rne_bits(XV[0] - __uint_as_float(h0_)); \
        unsigned int l1_ = bf16_rne_bits(XV[1] - __uint_as_float(h1_)); \
        unsigned int l2_ = bf16_rne_bits(XV[2] - __uint_as_float(h2_)); \
        unsigned int l3_ = bf16_rne_bits(XV[3] - __uint_as_float(h3_)); \
        int2 hp_ = make_int2((h0_ >> 16) | (h1_ & 0xFFFF0000u), \
                             (h2_ >> 16) | (h3_ & 0xFFFF0000u)); \
        int2 lp_ = make_int2((l0_ >> 16) | (l1_ & 0xFFFF0000u), \
                             (l2_ >> 16) | (l3_ & 0xFFFF0000u)); \
        *(int2*)(&albuf[BUF][spx * 64 + scg * 8])        = hp_; \
        *(int2*)(&albuf[BUF][7168 + spx * 64 + scg * 8]) = lp_; } while (0)

    // lane's B-fragment elem offset within a ks-chunk (nn adds 512)
    const int bfr = ((w * 32 + l15) * 4 + lg) * 8;

    #define COMPUTE(KS, BUF) do { \
        const unsigned short* bph_ = w1t_hi + (size_t)(KS) * 16384 + bfr; \
        const unsigned short* bpl_ = w1t_lo + (size_t)(KS) * 16384 + bfr; \
        const v8s bh0 = *(const v8s*)(bph_); \
        const v8s bh1 = *(const v8s*)(bph_ + 512); \
        const v8s bl0 = *(const v8s*)(bpl_); \
        const v8s bl1 = *(const v8s*)(bpl_ + 512); \
        const char* ab_ = &albuf[BUF][0]; \
        v8s ahr[7]; \
        _Pragma("unroll") for (int m = 0; m < 7; ++m) \
            ahr[m] = *(const v8s*)(ab_ + (m * 16 + l15) * 64 + lg * 16); \
        _Pragma("unroll") for (int m = 0; m < 7; ++m) \
            acc[m][0] = __builtin_amdgcn_mfma_f32_16x16x32_bf16(ahr[m], bh0, acc[m][0], 0, 0, 0); \
        _Pragma("unroll") for (int m = 0; m < 7; ++m) \
            acc[m][1] = __builtin_amdgcn_mfma_f32_16x16x32_bf16(ahr[m], bh1, acc[m][1], 0, 0, 0); \
        _Pragma("unroll") for (int m = 0; m < 7; ++m) \
            acc[m][0] = __builtin_amdgcn_mfma_f32_16x16x32_bf16(ahr[m], bl0, acc[m][0], 0, 0, 0); \
        _Pragma("unroll") for (int m = 0; m < 7; ++m) \
            acc[m][1] = __builtin_amdgcn_mfma_f32_16x16x32_bf16(ahr[m], bl1, acc[m][1], 0, 0, 0); \
        _Pragma("unroll") for (int m = 0; m < 7; ++m) { \
            const v8s alr = *(const v8s*)(ab_ + 7168 + (m * 16 + l15) * 64 + lg * 16); \
            acc[m][0] = __builtin_amdgcn_mfma_f32_16x16x32_bf16(alr, bh0, acc[m][0], 0, 0, 0); \
            acc[m][1] = __builtin_amdgcn_mfma_f32_16x16x32_bf16(alr, bh1, acc[m][1], 0, 0, 0); \
        } } while (0)

    if (stg) { A_LOAD(xa, 0); A_LOAD(xb, 1); A_WRITE(0, xa); }
    barrier_lds_only();

    for (int s = 0; s < 8; s += 2) {
        if (stg && s + 2 < 8) A_LOAD(xa, s + 2);   // stays in flight over barrier
        COMPUTE(s, 0);
        if (stg) A_WRITE(1, xb);                   // waits only xb's loads
        barrier_lds_only();
        if (stg && s + 3 < 8) A_LOAD(xb, s + 3);
        COMPUTE(s + 1, 1);
        if (stg && s + 2 < 8) A_WRITE(0, xa);
        barrier_lds_only();
    }

    // ---- epilogue: +text/bias, ReLU, *W2, reduce h within wave, LDS-reduce
    // across 16 waves, single plain store (no atomics, no memset needed) ----
    float tbn[2], w2n[2];
    #pragma unroll
    for (int nn = 0; nn < 2; ++nn) {
        const int h = w * 32 + nn * 16 + l15;
        const float* tp = tbp + (size_t)b * 8 * HID + h;
        float tv = b1[h];
        #pragma unroll
        for (int q = 0; q < 8; ++q) tv += tp[q * HID];
        tbn[nn] = tv;
        w2n[nn] = W2[h];
    }
    #pragma unroll
    for (int m = 0; m < 7; ++m) {
        #pragma unroll
        for (int r = 0; r < 4; ++r) {
            float s = 0.f;
            #pragma unroll
            for (int nn = 0; nn < 2; ++nn)
                s += fmaxf(acc[m][nn][r] + tbn[nn], 0.f) * w2n[nn];
            s += __shfl_xor(s, 1, 64);
            s += __shfl_xor(s, 2, 64);
            s += __shfl_xor(s, 4, 64);
            s += __shfl_xor(s, 8, 64);
            if (l15 == 0) sred[w * 112 + m * 16 + lg * 4 + r] = s;
        }
    }
    __syncthreads();
    if (tid < 112) {
        float s = 0.f;
        #pragma unroll
        for (int q = 0; q < 16; ++q) s += sred[q * 112 + tid];
        scores[b * PP + ptile * 112 + tid] = s;
    }
    #undef A_LOAD
    #undef A_WRITE
    #undef COMPUTE
}

// ---------------------------------------------------------------------------
// K3: softmax over P per batch row (in-place) + text passthrough (unchanged).
// (b2 omitted everywhere: softmax is shift-invariant.)
// ---------------------------------------------------------------------------
__global__ __launch_bounds__(256) void k_softmax_copy(float* __restrict__ sw,
                                                      const float* __restrict__ text,
                                                      float* __restrict__ out) {
    const int b   = blockIdx.x;
    const int tid = threadIdx.x;
    const int lane = tid & 63, wid = tid >> 6;
    __shared__ float red[4];

    float v[4]; int cnt = 0;
    float m = -3.4e38f;
    for (int p = tid; p < PP; p += 256) { v[cnt] = sw[b * PP + p]; m = fmaxf(m, v[cnt]); ++cnt; }
    #pragma unroll
    for (int off = 32; off > 0; off >>= 1) m = fmaxf(m, __shfl_xor(m, off, 64));
    if (lane == 0) red[wid] = m;
    __syncthreads();
    m = fmaxf(fmaxf(red[0], red[1]), fmaxf(red[2], red[3]));
    __syncthreads();

    float ssum = 0.f;
    for (int i = 0; i < cnt; ++i) { v[i] = expf(v[i] - m); ssum += v[i]; }
    #pragma unroll
    for (int off = 32; off > 0; off >>= 1) ssum += __shfl_xor(ssum, off, 64);
    if (lane == 0) red[wid] = ssum;
    __syncthreads();
    const float inv = 1.f / (red[0] + red[1] + red[2] + red[3]);

    cnt = 0;
    for (int p = tid; p < PP; p += 256) sw[b * PP + p] = v[cnt++] * inv;

    for (int j = tid; j < TT; j += 256) out[b * FF + CC + j] = text[b * TT + j];
}

// ---------------------------------------------------------------------------
// K4: pooled[b,c] = sum_p vision[b,c,p] * weights[b,p]  (unchanged).
// ---------------------------------------------------------------------------
__global__ __launch_bounds__(256) void k_pool(const float* __restrict__ vision,
                                              const float* __restrict__ wts,
                                              float* __restrict__ out) {
    const int cg = blockIdx.x;   // 8 channel groups of 32
    const int b  = blockIdx.y;
    const int tid = threadIdx.x, lane = tid & 63, wid = tid >> 6;  // 4 waves
    __shared__ float wl[PP];
    {
        const int i = tid * 4;
        if (i < PP) *(float4*)&wl[i] = *(const float4*)&wts[b * PP + i];
    }
    __syncthreads();
    #pragma unroll
    for (int ci = 0; ci < 8; ++ci) {
        const int c = cg * 32 + wid * 8 + ci;
        const float* vr = vision + (size_t)b * (CC * PP) + (size_t)c * PP;
        float acc = 0.f;
        #pragma unroll
        for (int k = 0; k < 4; ++k) {
            const int p4 = (lane + 64 * k) * 4;
            if (p4 < PP) {
                const float4 vv = *(const float4*)(vr + p4);
                const float4 ww = *(const float4*)&wl[p4];
                acc = fmaf(vv.x, ww.x, acc);
                acc = fmaf(vv.y, ww.y, acc);
                acc = fmaf(vv.z, ww.z, acc);
                acc = fmaf(vv.w, ww.w, acc);
            }
        }
        #pragma unroll
        for (int off = 32; off > 0; off >>= 1) acc += __shfl_xor(acc, off, 64);
        if (lane == 0) out[b * FF + c] = acc;
    }
}

// ---------------------------------------------------------------------------
extern "C" void kernel_launch(void* const* d_in, const int* in_sizes, int n_in,
                              void* d_out, int out_size, void* d_ws, size_t ws_size,
                              hipStream_t stream) {
    const float* text   = (const float*)d_in[0];
    const float* vision = (const float*)d_in[1];
    const float* W1     = (const float*)d_in[2];
    const float* b1     = (const float*)d_in[3];
    const float* W2     = (const float*)d_in[4];
    float* out = (float*)d_out;

    // ws layout: tbp 1MB | sw 200KB | w1t_hi 256KB | w1t_lo 256KB  (~1.7 MB)
    float* tbp = (float*)d_ws;                       // 64*8*512 f32
    float* sw  = tbp + BB * 8 * HID;                 // 64*784 f32
    unsigned short* w1t_hi = (unsigned short*)(sw + BB * PP);   // 131072 bf16
    unsigned short* w1t_lo = w1t_hi + 131072;

    k_w1t        <<<64, 256, 0, stream>>>(W1, w1t_hi, w1t_lo);
    k_text_gemm  <<<dim3(BB, 8), 512, 0, stream>>>(text, W1, tbp);
    k_vision_mfma<<<dim3(7, BB), 1024, 0, stream>>>(vision, w1t_hi, w1t_lo,
                                                    b1, W2, tbp, sw);
    k_softmax_copy<<<BB, 256, 0, stream>>>(sw, text, out);
    k_pool       <<<dim3(8, BB), 256, 0, stream>>>(vision, sw, out);
}

// Round 11
// 178.268 us; speedup vs baseline: 1.0751x; 1.0751x over previous
//
#include <hip/hip_runtime.h>

#define BB  64
#define TT  1024
#define CC  256
#define PP  784     // 28*28
#define HID 512
#define FF  1280    // CC + TT

typedef float v4f __attribute__((ext_vector_type(4)));
typedef short v8s __attribute__((ext_vector_type(8)));

// round-to-nearest-even bf16; returns the f32 bit pattern of the bf16 value
__device__ inline unsigned int bf16_rne_bits(float x) {
    unsigned int u = __float_as_uint(x);
    unsigned int r = u + 0x7FFFu + ((u >> 16) & 1u);
    return r & 0xFFFF0000u;
}

// barrier that does NOT drain vmcnt: LDS-visibility only (validated r10:
// passed with identical absmax). In-flight global loads survive across it.
__device__ inline void barrier_lds_only() {
    asm volatile("s_waitcnt lgkmcnt(0)" ::: "memory");
    __builtin_amdgcn_s_barrier();
}

// ---------------------------------------------------------------------------
// K0: W1 vision-half -> bf16 hi/lo, fragment-image order, full-512h chunks:
// chunk ks (16384 elems) holds h*32 + g*8 + e, where c = ks*32 + g*8 + e.
// ---------------------------------------------------------------------------
__global__ __launch_bounds__(256) void k_w1t(const float* __restrict__ W1,
                                             unsigned short* __restrict__ w1t_hi,
                                             unsigned short* __restrict__ w1t_lo) {
    const int id = blockIdx.x * 256 + threadIdx.x;   // 16384 threads
    const int ks = id >> 11;          // 0..7
    const int h  = (id >> 2) & 511;
    const int g  = id & 3;
    const float* W1v = W1 + (size_t)TT * HID;
    unsigned int hw[4], lw[4];
    #pragma unroll
    for (int k = 0; k < 4; ++k) {
        const int c0 = ks * 32 + g * 8 + 2 * k;
        float x0 = W1v[(size_t)c0 * HID + h];
        float x1 = W1v[(size_t)(c0 + 1) * HID + h];
        unsigned int h0 = bf16_rne_bits(x0), h1 = bf16_rne_bits(x1);
        unsigned int l0 = bf16_rne_bits(x0 - __uint_as_float(h0));
        unsigned int l1 = bf16_rne_bits(x1 - __uint_as_float(h1));
        hw[k] = (h0 >> 16) | (h1 & 0xFFFF0000u);
        lw[k] = (l0 >> 16) | (l1 & 0xFFFF0000u);
    }
    *(int4*)(&w1t_hi[(size_t)id * 8]) = make_int4(hw[0], hw[1], hw[2], hw[3]);
    *(int4*)(&w1t_lo[(size_t)id * 8]) = make_int4(lw[0], lw[1], lw[2], lw[3]);
}

// ---------------------------------------------------------------------------
// K1: text GEMM partials, k-split by 8 (unchanged).
// ---------------------------------------------------------------------------
__global__ __launch_bounds__(512) void k_text_gemm(const float* __restrict__ text,
                                                   const float* __restrict__ W1,
                                                   float* __restrict__ tbp) {
    const int b  = blockIdx.x;
    const int ks = blockIdx.y;    // 0..7
    const int t  = threadIdx.x;
    __shared__ float st[128];
    if (t < 128) st[t] = text[b * TT + ks * 128 + t];
    __syncthreads();
    float acc = 0.f;
    const float* wp = W1 + (size_t)(ks * 128) * HID + t;
    #pragma unroll 4
    for (int k = 0; k < 128; ++k)
        acc = fmaf(st[k], wp[(size_t)k * HID], acc);
    tbp[(b * 8 + ks) * HID + t] = acc;
}

// ---------------------------------------------------------------------------
// K2 (hot): vision GEMM, bf16 hi/lo 3-term MFMA.
// 256 thr / 4 waves (round-6 proven skeleton). Block = 112 px x 128 h
// (hh 4-way split; vision re-reads L3-absorbed). Wave = 7m x 2n -> acc 56
// -> ~150 unified regs -> 3 waves/SIMD via __launch_bounds__(256,3).
// A double-buffered LDS (load-early/write-late), barrier_lds_only (no vmcnt
// drain), pass-split MFMAs, B fragment-direct from L2.
// Writes per-hh partial scores (no atomics); K3 sums the 4 planes.
// ---------------------------------------------------------------------------
__global__ __launch_bounds__(256, 3) void k_vision_mfma(
        const float* __restrict__ vision,
        const unsigned short* __restrict__ w1t_hi,
        const unsigned short* __restrict__ w1t_lo,
        const float* __restrict__ b1,
        const float* __restrict__ W2,
        const float* __restrict__ tbp,
        float* __restrict__ spart) {   // [4][BB][PP]
    const int ptile = blockIdx.x;   // 0..6
    const int hh    = blockIdx.y;   // 0..3
    const int b     = blockIdx.z;
    const int tid   = threadIdx.x;
    const int lane  = tid & 63;
    const int w     = tid >> 6;     // 0..3
    const int l15   = lane & 15, lg = lane >> 4;

    __shared__ char albuf[2][14336];     // [buf][hi 7168 | lo 7168]
    __shared__ float sred[4 * 112];

    v4f acc[7][2];
    #pragma unroll
    for (int m = 0; m < 7; ++m) {
        acc[m][0] = (v4f){0.f, 0.f, 0.f, 0.f};
        acc[m][1] = (v4f){0.f, 0.f, 0.f, 0.f};
    }

    const size_t vbase = (size_t)b * (CC * PP) + ptile * 112;
    const int spx = tid >> 1, sch = tid & 1;   // staging map (tid < 224)
    const bool stg = (tid < 224);

    float xa[16], xb[16];

    #define A_LOAD(XV, KS) do { \
        _Pragma("unroll") for (int j = 0; j < 16; ++j) { \
            const int c_ = (KS) * 32 + sch * 16 + j; \
            XV[j] = vision[vbase + (size_t)c_ * PP + spx]; } } while (0)

    #define A_WRITE(BUF, XV) do { \
        unsigned int hw[8], lw[8]; \
        _Pragma("unroll") for (int q = 0; q < 8; ++q) { \
            unsigned int h0 = bf16_rne_bits(XV[2 * q]); \
            unsigned int h1 = bf16_rne_bits(XV[2 * q + 1]); \
            unsigned int l0 = bf16_rne_bits(XV[2 * q] - __uint_as_float(h0)); \
            unsigned int l1 = bf16_rne_bits(XV[2 * q + 1] - __uint_as_float(h1)); \
            hw[q] = (h0 >> 16) | (h1 & 0xFFFF0000u); \
            lw[q] = (l0 >> 16) | (l1 & 0xFFFF0000u); } \
        int4* ah = (int4*)(&albuf[BUF][0]) + (spx * 4 + sch * 2); \
        int4* al = (int4*)(&albuf[BUF][7168]) + (spx * 4 + sch * 2); \
        ah[0] = make_int4(hw[0], hw[1], hw[2], hw[3]); \
        ah[1] = make_int4(hw[4], hw[5], hw[6], hw[7]); \
        al[0] = make_int4(lw[0], lw[1], lw[2], lw[3]); \
        al[1] = make_int4(lw[4], lw[5], lw[6], lw[7]); } while (0)

    // lane's B-fragment elem offset within a ks-chunk; nn adds 512
    const int bfr = (hh * 128 + w * 32 + l15) * 32 + lg * 8;

    #define COMPUTE(KS, BUF) do { \
        const unsigned short* bph_ = w1t_hi + (size_t)(KS) * 16384 + bfr; \
        const unsigned short* bpl_ = w1t_lo + (size_t)(KS) * 16384 + bfr; \
        const v8s bh0 = *(const v8s*)(bph_); \
        const v8s bh1 = *(const v8s*)(bph_ + 512); \
        const v8s bl0 = *(const v8s*)(bpl_); \
        const v8s bl1 = *(const v8s*)(bpl_ + 512); \
        const char* ab_ = &albuf[BUF][0]; \
        v8s ahr[7]; \
        _Pragma("unroll") for (int m = 0; m < 7; ++m) \
            ahr[m] = *(const v8s*)(ab_ + (m * 16 + l15) * 64 + lg * 16); \
        _Pragma("unroll") for (int m = 0; m < 7; ++m) \
            acc[m][0] = __builtin_amdgcn_mfma_f32_16x16x32_bf16(ahr[m], bh0, acc[m][0], 0, 0, 0); \
        _Pragma("unroll") for (int m = 0; m < 7; ++m) \
            acc[m][1] = __builtin_amdgcn_mfma_f32_16x16x32_bf16(ahr[m], bh1, acc[m][1], 0, 0, 0); \
        _Pragma("unroll") for (int m = 0; m < 7; ++m) \
            acc[m][0] = __builtin_amdgcn_mfma_f32_16x16x32_bf16(ahr[m], bl0, acc[m][0], 0, 0, 0); \
        _Pragma("unroll") for (int m = 0; m < 7; ++m) \
            acc[m][1] = __builtin_amdgcn_mfma_f32_16x16x32_bf16(ahr[m], bl1, acc[m][1], 0, 0, 0); \
        _Pragma("unroll") for (int m = 0; m < 7; ++m) { \
            const v8s alr = *(const v8s*)(ab_ + 7168 + (m * 16 + l15) * 64 + lg * 16); \
            acc[m][0] = __builtin_amdgcn_mfma_f32_16x16x32_bf16(alr, bh0, acc[m][0], 0, 0, 0); \
            acc[m][1] = __builtin_amdgcn_mfma_f32_16x16x32_bf16(alr, bh1, acc[m][1], 0, 0, 0); \
        } } while (0)

    if (stg) { A_LOAD(xa, 0); A_LOAD(xb, 1); A_WRITE(0, xa); }
    barrier_lds_only();

    for (int s = 0; s < 8; s += 2) {
        if (stg && s + 2 < 8) A_LOAD(xa, s + 2);   // in flight over barrier
        COMPUTE(s, 0);
        if (stg) A_WRITE(1, xb);                   // waits only xb's loads
        barrier_lds_only();
        if (stg && s + 3 < 8) A_LOAD(xb, s + 3);
        COMPUTE(s + 1, 1);
        if (stg && s + 2 < 8) A_WRITE(0, xa);
        barrier_lds_only();
    }

    // ---- epilogue: +text/bias, ReLU, *W2, reduce h in wave, LDS-reduce
    // across 4 waves, plain store of this hh's partial (no atomics) ----
    float tbn[2], w2n[2];
    #pragma unroll
    for (int nn = 0; nn < 2; ++nn) {
        const int h = hh * 128 + w * 32 + nn * 16 + l15;
        const float* tp = tbp + (size_t)b * 8 * HID + h;
        float tv = b1[h];
        #pragma unroll
        for (int q = 0; q < 8; ++q) tv += tp[q * HID];
        tbn[nn] = tv;
        w2n[nn] = W2[h];
    }
    #pragma unroll
    for (int m = 0; m < 7; ++m) {
        #pragma unroll
        for (int r = 0; r < 4; ++r) {
            float s = 0.f;
            #pragma unroll
            for (int nn = 0; nn < 2; ++nn)
                s += fmaxf(acc[m][nn][r] + tbn[nn], 0.f) * w2n[nn];
            s += __shfl_xor(s, 1, 64);
            s += __shfl_xor(s, 2, 64);
            s += __shfl_xor(s, 4, 64);
            s += __shfl_xor(s, 8, 64);
            if (l15 == 0) sred[w * 112 + m * 16 + lg * 4 + r] = s;
        }
    }
    __syncthreads();
    if (tid < 112) {
        float s = sred[tid] + sred[112 + tid] + sred[224 + tid] + sred[336 + tid];
        spart[((size_t)hh * BB + b) * PP + ptile * 112 + tid] = s;
    }
    #undef A_LOAD
    #undef A_WRITE
    #undef COMPUTE
}

// ---------------------------------------------------------------------------
// K3: sum 4 hh-planes, softmax over P per batch row (into plane 0),
// plus text passthrough. (b2 omitted: softmax shift-invariant.)
// ---------------------------------------------------------------------------
__global__ __launch_bounds__(256) void k_softmax_copy(float* __restrict__ sw,
                                                      const float* __restrict__ text,
                                                      float* __restrict__ out) {
    const int b   = blockIdx.x;
    const int tid = threadIdx.x;
    const int lane = tid & 63, wid = tid >> 6;
    __shared__ float red[4];
    const size_t pl = (size_t)BB * PP;

    float v[4]; int cnt = 0;
    float m = -3.4e38f;
    for (int p = tid; p < PP; p += 256) {
        const size_t o = (size_t)b * PP + p;
        v[cnt] = sw[o] + sw[pl + o] + sw[2 * pl + o] + sw[3 * pl + o];
        m = fmaxf(m, v[cnt]); ++cnt;
    }
    #pragma unroll
    for (int off = 32; off > 0; off >>= 1) m = fmaxf(m, __shfl_xor(m, off, 64));
    if (lane == 0) red[wid] = m;
    __syncthreads();
    m = fmaxf(fmaxf(red[0], red[1]), fmaxf(red[2], red[3]));
    __syncthreads();

    float ssum = 0.f;
    for (int i = 0; i < cnt; ++i) { v[i] = expf(v[i] - m); ssum += v[i]; }
    #pragma unroll
    for (int off = 32; off > 0; off >>= 1) ssum += __shfl_xor(ssum, off, 64);
    if (lane == 0) red[wid] = ssum;
    __syncthreads();
    const float inv = 1.f / (red[0] + red[1] + red[2] + red[3]);

    cnt = 0;
    for (int p = tid; p < PP; p += 256) sw[(size_t)b * PP + p] = v[cnt++] * inv;

    for (int j = tid; j < TT; j += 256) out[b * FF + CC + j] = text[b * TT + j];
}

// ---------------------------------------------------------------------------
// K4: pooled[b,c] = sum_p vision[b,c,p] * weights[b,p]  (unchanged).
// ---------------------------------------------------------------------------
__global__ __launch_bounds__(256) void k_pool(const float* __restrict__ vision,
                                              const float* __restrict__ wts,
                                              float* __restrict__ out) {
    const int cg = blockIdx.x;   // 8 channel groups of 32
    const int b  = blockIdx.y;
    const int tid = threadIdx.x, lane = tid & 63, wid = tid >> 6;  // 4 waves
    __shared__ float wl[PP];
    {
        const int i = tid * 4;
        if (i < PP) *(float4*)&wl[i] = *(const float4*)&wts[(size_t)b * PP + i];
    }
    __syncthreads();
    #pragma unroll
    for (int ci = 0; ci < 8; ++ci) {
        const int c = cg * 32 + wid * 8 + ci;
        const float* vr = vision + (size_t)b * (CC * PP) + (size_t)c * PP;
        float acc = 0.f;
        #pragma unroll
        for (int k = 0; k < 4; ++k) {
            const int p4 = (lane + 64 * k) * 4;
            if (p4 < PP) {
                const float4 vv = *(const float4*)(vr + p4);
                const float4 ww = *(const float4*)&wl[p4];
                acc = fmaf(vv.x, ww.x, acc);
                acc = fmaf(vv.y, ww.y, acc);
                acc = fmaf(vv.z, ww.z, acc);
                acc = fmaf(vv.w, ww.w, acc);
            }
        }
        #pragma unroll
        for (int off = 32; off > 0; off >>= 1) acc += __shfl_xor(acc, off, 64);
        if (lane == 0) out[b * FF + c] = acc;
    }
}

// ---------------------------------------------------------------------------
extern "C" void kernel_launch(void* const* d_in, const int* in_sizes, int n_in,
                              void* d_out, int out_size, void* d_ws, size_t ws_size,
                              hipStream_t stream) {
    const float* text   = (const float*)d_in[0];
    const float* vision = (const float*)d_in[1];
    const float* W1     = (const float*)d_in[2];
    const float* b1     = (const float*)d_in[3];
    const float* W2     = (const float*)d_in[4];
    float* out = (float*)d_out;

    // ws: tbp 1MB | spart 4 planes 800KB | w1t_hi 256KB | w1t_lo 256KB (~2.3MB)
    float* tbp = (float*)d_ws;                       // 64*8*512 f32
    float* sw  = tbp + BB * 8 * HID;                 // 4 * 64*784 f32
    unsigned short* w1t_hi = (unsigned short*)(sw + 4 * BB * PP);
    unsigned short* w1t_lo = w1t_hi + 131072;

    k_w1t        <<<64, 256, 0, stream>>>(W1, w1t_hi, w1t_lo);
    k_text_gemm  <<<dim3(BB, 8), 512, 0, stream>>>(text, W1, tbp);
    k_vision_mfma<<<dim3(7, 4, BB), 256, 0, stream>>>(vision, w1t_hi, w1t_lo,
                                                      b1, W2, tbp, sw);
    k_softmax_copy<<<BB, 256, 0, stream>>>(sw, text, out);
    k_pool       <<<dim3(8, BB), 256, 0, stream>>>(vision, sw, out);
}